// Round 1
// baseline (400.009 us; speedup 1.0000x reference)
//
#include <hip/hip_runtime.h>
#include <math.h>

#define DM 192
#define DI 384
#define DS 16
#define DTR 12
#define BB 4
#define LL 3136
#define NTOK (BB*LL)
#define CHUNK 56
#define NCH (LL/CHUNK)

__device__ __forceinline__ float warp_sum64(float v){
  #pragma unroll
  for (int m=32;m>=1;m>>=1) v += __shfl_xor(v, m, 64);
  return v;
}

// ---------------- K1: LayerNorm (one wave per token, 3 elems/lane) -------------
__global__ __launch_bounds__(64) void k_ln(const float* __restrict__ x,
    const float* __restrict__ w, const float* __restrict__ b, float* __restrict__ h)
{
  int tok = blockIdx.x;
  int lane = threadIdx.x;
  const float* xr = x + (size_t)tok*DM;
  float v0 = xr[lane], v1 = xr[lane+64], v2 = xr[lane+128];
  float s = warp_sum64(v0+v1+v2);
  float mu = s * (1.0f/DM);
  float d0=v0-mu, d1=v1-mu, d2=v2-mu;
  float s2 = warp_sum64(d0*d0+d1*d1+d2*d2);
  float rs = rsqrtf(s2*(1.0f/DM) + 1e-5f);
  float* hr = h + (size_t)tok*DM;
  hr[lane]     = d0*rs*w[lane]     + b[lane];
  hr[lane+64]  = d1*rs*w[lane+64]  + b[lane+64];
  hr[lane+128] = d2*rs*w[lane+128] + b[lane+128];
}

// ---------------- Tiled fp32 GEMM: C[M,N] = A[M,K] @ B[K,N] -------------------
// BM=BN=64, BK=16, 256 threads, 4x4 microtile. M%64==0, N%64==0, K%16==0.
__global__ __launch_bounds__(256) void k_sgemm(const float* __restrict__ A,
  const float* __restrict__ Bm, float* __restrict__ C, int M, int N, int K)
{
  const int BM=64, BN=64, BK=16;
  __shared__ float As[BK][BM+4];
  __shared__ float Bs[BK][BN];
  int tid = threadIdx.x;
  int bm = blockIdx.y*BM, bn = blockIdx.x*BN;
  int tr = tid/16, tc = tid%16;
  float acc[4][4] = {};
  int a_row = tid/4;          // 0..63
  int a_c4  = (tid%4)*4;      // 0,4,8,12
  int b_row = tid/16;         // 0..15
  int b_c4  = (tid%16)*4;
  for (int k0=0;k0<K;k0+=BK){
    float4 av = *(const float4*)&A[(size_t)(bm+a_row)*K + k0 + a_c4];
    As[a_c4+0][a_row]=av.x;
    As[a_c4+1][a_row]=av.y;
    As[a_c4+2][a_row]=av.z;
    As[a_c4+3][a_row]=av.w;
    *(float4*)&Bs[b_row][b_c4] = *(const float4*)&Bm[(size_t)(k0+b_row)*N + bn + b_c4];
    __syncthreads();
    #pragma unroll
    for (int k=0;k<BK;++k){
      float4 a4 = *(const float4*)&As[k][tr*4];
      float4 b4 = *(const float4*)&Bs[k][tc*4];
      float ar[4] = {a4.x,a4.y,a4.z,a4.w};
      float br[4] = {b4.x,b4.y,b4.z,b4.w};
      #pragma unroll
      for (int i=0;i<4;++i)
        #pragma unroll
        for (int j=0;j<4;++j)
          acc[i][j] += ar[i]*br[j];
    }
    __syncthreads();
  }
  #pragma unroll
  for (int i=0;i<4;++i){
    float4 o; o.x=acc[i][0]; o.y=acc[i][1]; o.z=acc[i][2]; o.w=acc[i][3];
    *(float4*)&C[(size_t)(bm+tr*4+i)*N + bn + tc*4] = o;
  }
}

// ---------------- K3: depthwise causal conv (k=4) + bias + SiLU ---------------
__global__ __launch_bounds__(256) void k_conv(const float* __restrict__ xz,
  const float* __restrict__ cw, const float* __restrict__ cb, float* __restrict__ u)
{
  int g = blockIdx.x*256 + threadIdx.x;
  if (g >= NTOK*DI) return;
  int d = g % DI;
  int tok = g / DI;
  int l = tok % LL;
  float acc = cb[d];
  float w0=cw[d*4+0], w1=cw[d*4+1], w2=cw[d*4+2], w3=cw[d*4+3];
  const float* base = xz + (size_t)tok*768 + d;
  if (l>=3) acc += base[-3*768]*w0;
  if (l>=2) acc += base[-2*768]*w1;
  if (l>=1) acc += base[-1*768]*w2;
  acc += base[0]*w3;
  float sil = acc/(1.0f+__expf(-acc));
  u[g] = sil;
}

// ---------------- K4a: x_dbl = u @ x_proj_w (N=44), split dt/Bc/Cc -----------
__global__ __launch_bounds__(256) void k_xproj(const float* __restrict__ u,
  const float* __restrict__ W, float* __restrict__ dt, float* __restrict__ Bc,
  float* __restrict__ Cc)
{
  int wid = threadIdx.x >> 6;
  int lane = threadIdx.x & 63;
  int tok = blockIdx.x*4 + wid;
  if (tok >= NTOK) return;
  const float* ur = u + (size_t)tok*DI;
  if (lane < 44) {
    float acc = 0.f;
    for (int k=0;k<DI;k+=4){
      float4 uv = *(const float4*)&ur[k];
      acc += uv.x*W[(k+0)*44+lane];
      acc += uv.y*W[(k+1)*44+lane];
      acc += uv.z*W[(k+2)*44+lane];
      acc += uv.w*W[(k+3)*44+lane];
    }
    if (lane < DTR) dt[(size_t)tok*DTR+lane] = acc;
    else if (lane < DTR+DS) Bc[(size_t)tok*DS + (lane-DTR)] = acc;
    else Cc[(size_t)tok*DS + (lane-DTR-DS)] = acc;
  }
}

// ---------------- K4b: delta = softplus(dt @ dt_proj_w + b) ------------------
__global__ __launch_bounds__(256) void k_delta(const float* __restrict__ dt,
  const float* __restrict__ W, const float* __restrict__ bias, float* __restrict__ delta)
{
  int g = blockIdx.x*256+threadIdx.x;
  if (g >= NTOK*DI) return;
  int d = g % DI; int tok = g / DI;
  float acc = bias[d];
  #pragma unroll
  for (int r=0;r<DTR;++r) acc += dt[(size_t)tok*DTR+r]*W[r*DI+d];
  float sp = fmaxf(acc,0.f) + log1pf(__expf(-fabsf(acc)));
  delta[g] = sp;
}

// ---------------- K5a: chunk-local scan (h from 0) + running dA product ------
__global__ __launch_bounds__(256) void k_scanA(const float* __restrict__ delta,
  const float* __restrict__ u, const float* __restrict__ Bc, const float* __restrict__ Alog,
  float* __restrict__ apb, float* __restrict__ heb)
{
  int g = blockIdx.x*256+threadIdx.x;
  if (g >= BB*NCH*DI) return;
  int d = g % DI;
  int c = (g/DI) % NCH;
  int b = g/(DI*NCH);
  float A[DS], h[DS], ap[DS];
  #pragma unroll
  for (int n=0;n<DS;++n){ A[n] = -__expf(Alog[d*DS+n]); h[n]=0.f; ap[n]=1.f; }
  int t0 = c*CHUNK;
  for (int t=t0; t<t0+CHUNK; ++t){
    size_t tok = (size_t)b*LL + t;
    float dl = delta[tok*DI + d];
    float uu = u[tok*DI + d];
    float du = dl*uu;
    const float* bcr = Bc + tok*DS;
    #pragma unroll
    for (int n=0;n<DS;++n){
      float dA = __expf(dl*A[n]);
      h[n] = dA*h[n] + du*bcr[n];
      ap[n] *= dA;
    }
  }
  size_t off = ((size_t)(b*NCH + c)*DI + d)*DS;
  #pragma unroll
  for (int n=0;n<DS;++n){ apb[off+n]=ap[n]; heb[off+n]=h[n]; }
}

// ---------------- K5b: cross-chunk scan (tiny) -------------------------------
__global__ __launch_bounds__(256) void k_scanB(const float* __restrict__ apb,
  const float* __restrict__ heb, float* __restrict__ hsb)
{
  int g = blockIdx.x*256+threadIdx.x;
  if (g >= BB*DI) return;
  int d = g % DI; int b = g / DI;
  float h[DS];
  #pragma unroll
  for (int n=0;n<DS;++n) h[n]=0.f;
  for (int c=0;c<NCH;++c){
    size_t off = ((size_t)(b*NCH+c)*DI + d)*DS;
    #pragma unroll
    for (int n=0;n<DS;++n) hsb[off+n] = h[n];
    #pragma unroll
    for (int n=0;n<DS;++n) h[n] = apb[off+n]*h[n] + heb[off+n];
  }
}

// ---------------- K5c: re-scan with true h_start, fused epilogue -------------
// outpre may alias delta (each element read then written by the same thread).
__global__ __launch_bounds__(256) void k_scanC(const float* __restrict__ delta_in,
  const float* __restrict__ u, const float* __restrict__ Bc, const float* __restrict__ Cc,
  const float* __restrict__ Alog, const float* __restrict__ Dskip,
  const float* __restrict__ xz, const float* __restrict__ hsb, float* __restrict__ outpre)
{
  int g = blockIdx.x*256+threadIdx.x;
  if (g >= BB*NCH*DI) return;
  int d = g % DI;
  int c = (g/DI) % NCH;
  int b = g/(DI*NCH);
  float A[DS], h[DS];
  size_t off = ((size_t)(b*NCH + c)*DI + d)*DS;
  #pragma unroll
  for (int n=0;n<DS;++n){ A[n] = -__expf(Alog[d*DS+n]); h[n]=hsb[off+n]; }
  float dsk = Dskip[d];
  int t0 = c*CHUNK;
  for (int t=t0; t<t0+CHUNK; ++t){
    size_t tok = (size_t)b*LL + t;
    float dl = delta_in[tok*DI + d];
    float uu = u[tok*DI + d];
    float du = dl*uu;
    const float* bcr = Bc + tok*DS;
    const float* ccr = Cc + tok*DS;
    float y = 0.f;
    #pragma unroll
    for (int n=0;n<DS;++n){
      float dA = __expf(dl*A[n]);
      h[n] = dA*h[n] + du*bcr[n];
      y += h[n]*ccr[n];
    }
    y += uu*dsk;
    float z = xz[tok*768 + 384 + d];
    float sil = z/(1.0f+__expf(-z));
    outpre[tok*DI + d] = y*sil;
  }
}

extern "C" void kernel_launch(void* const* d_in, const int* in_sizes, int n_in,
                              void* d_out, int out_size, void* d_ws, size_t ws_size,
                              hipStream_t stream) {
  const float* x         = (const float*)d_in[0];
  const float* ln_w      = (const float*)d_in[1];
  const float* ln_b      = (const float*)d_in[2];
  const float* in_proj_w = (const float*)d_in[3];
  const float* conv_w    = (const float*)d_in[4];
  const float* conv_b    = (const float*)d_in[5];
  const float* x_proj_w  = (const float*)d_in[6];
  const float* dt_proj_w = (const float*)d_in[7];
  const float* dt_proj_b = (const float*)d_in[8];
  const float* A_log     = (const float*)d_in[9];
  const float* D_skip    = (const float*)d_in[10];
  const float* out_proj_w= (const float*)d_in[11];
  float* out = (float*)d_out;

  float* ws = (float*)d_ws;
  size_t off = 0;
  float* hbuf  = ws + off; off += (size_t)NTOK*DM;      // 2.41M
  float* xz    = ws + off; off += (size_t)NTOK*768;     // 9.63M
  float* ubuf  = ws + off; off += (size_t)NTOK*DI;      // 4.82M
  float* delta = ws + off; off += (size_t)NTOK*DI;      // 4.82M (reused as outpre)
  float* Bcb   = ws + off; off += (size_t)NTOK*DS;
  float* Ccb   = ws + off; off += (size_t)NTOK*DS;
  float* dtb   = ws + off; off += (size_t)NTOK*DTR;
  float* apb   = ws + off; off += (size_t)BB*NCH*DI*DS; // 1.38M
  float* heb   = ws + off; off += (size_t)BB*NCH*DI*DS;
  float* hsb   = ws + off; off += (size_t)BB*NCH*DI*DS;

  // 1. LayerNorm
  k_ln<<<NTOK, 64, 0, stream>>>(x, ln_w, ln_b, hbuf);
  // 2. in_proj GEMM: [12544,192] @ [192,768]
  {
    dim3 g(768/64, NTOK/64);
    k_sgemm<<<g, 256, 0, stream>>>(hbuf, in_proj_w, xz, NTOK, 768, DM);
  }
  // 3. conv + SiLU
  k_conv<<<(NTOK*DI)/256, 256, 0, stream>>>(xz, conv_w, conv_b, ubuf);
  // 4a. x_proj
  k_xproj<<<NTOK/4, 256, 0, stream>>>(ubuf, x_proj_w, dtb, Bcb, Ccb);
  // 4b. dt_proj + softplus
  k_delta<<<(NTOK*DI)/256, 256, 0, stream>>>(dtb, dt_proj_w, dt_proj_b, delta);
  // 5. chunked scan
  k_scanA<<<(BB*NCH*DI)/256, 256, 0, stream>>>(delta, ubuf, Bcb, A_log, apb, heb);
  k_scanB<<<(BB*DI)/256, 256, 0, stream>>>(apb, heb, hsb);
  k_scanC<<<(BB*NCH*DI)/256, 256, 0, stream>>>(delta, ubuf, Bcb, Ccb, A_log, D_skip,
                                               xz, hsb, delta /*outpre in-place*/);
  // 6. out_proj GEMM: [12544,384] @ [384,192] -> d_out
  {
    dim3 g(192/64, NTOK/64);
    k_sgemm<<<g, 256, 0, stream>>>(delta, out_proj_w, out, NTOK, 192, DI);
  }
}

// Round 2
// 351.563 us; speedup vs baseline: 1.1378x; 1.1378x over previous
//
#include <hip/hip_runtime.h>
#include <math.h>

#define DM 192
#define DI 384
#define DS 16
#define DTR 12
#define BB 4
#define LL 3136
#define NTOK (BB*LL)
#define CHUNK 56
#define NCH (LL/CHUNK)
#define XDW 64   // padded x_dbl width (44 real cols: 12 dt, 16 B, 16 C)

__device__ __forceinline__ float warp_sum64(float v){
  #pragma unroll
  for (int m=32;m>=1;m>>=1) v += __shfl_xor(v, m, 64);
  return v;
}

// ---------------- K1: LayerNorm (one wave per token, 3 elems/lane) -------------
__global__ __launch_bounds__(64) void k_ln(const float* __restrict__ x,
    const float* __restrict__ w, const float* __restrict__ b, float* __restrict__ h)
{
  int tok = blockIdx.x;
  int lane = threadIdx.x;
  const float* xr = x + (size_t)tok*DM;
  float v0 = xr[lane], v1 = xr[lane+64], v2 = xr[lane+128];
  float s = warp_sum64(v0+v1+v2);
  float mu = s * (1.0f/DM);
  float d0=v0-mu, d1=v1-mu, d2=v2-mu;
  float s2 = warp_sum64(d0*d0+d1*d1+d2*d2);
  float rs = rsqrtf(s2*(1.0f/DM) + 1e-5f);
  float* hr = h + (size_t)tok*DM;
  hr[lane]     = d0*rs*w[lane]     + b[lane];
  hr[lane+64]  = d1*rs*w[lane+64]  + b[lane+64];
  hr[lane+128] = d2*rs*w[lane+128] + b[lane+128];
}

// ---------------- Tiled fp32 GEMM: C[M,N] = A[M,K] @ B[K,N] -------------------
// BM=BN=64, BK=16, 256 threads, 4x4 microtile. M%64==0, N%64==0, K%16==0.
__global__ __launch_bounds__(256) void k_sgemm(const float* __restrict__ A,
  const float* __restrict__ Bm, float* __restrict__ C, int M, int N, int K)
{
  const int BM=64, BN=64, BK=16;
  __shared__ float As[BK][BM+4];
  __shared__ float Bs[BK][BN];
  int tid = threadIdx.x;
  int bm = blockIdx.y*BM, bn = blockIdx.x*BN;
  int tr = tid/16, tc = tid%16;
  float acc[4][4] = {};
  int a_row = tid/4;          // 0..63
  int a_c4  = (tid%4)*4;      // 0,4,8,12
  int b_row = tid/16;         // 0..15
  int b_c4  = (tid%16)*4;
  for (int k0=0;k0<K;k0+=BK){
    float4 av = *(const float4*)&A[(size_t)(bm+a_row)*K + k0 + a_c4];
    As[a_c4+0][a_row]=av.x;
    As[a_c4+1][a_row]=av.y;
    As[a_c4+2][a_row]=av.z;
    As[a_c4+3][a_row]=av.w;
    *(float4*)&Bs[b_row][b_c4] = *(const float4*)&Bm[(size_t)(k0+b_row)*N + bn + b_c4];
    __syncthreads();
    #pragma unroll
    for (int k=0;k<BK;++k){
      float4 a4 = *(const float4*)&As[k][tr*4];
      float4 b4 = *(const float4*)&Bs[k][tc*4];
      float ar[4] = {a4.x,a4.y,a4.z,a4.w};
      float br[4] = {b4.x,b4.y,b4.z,b4.w};
      #pragma unroll
      for (int i=0;i<4;++i)
        #pragma unroll
        for (int j=0;j<4;++j)
          acc[i][j] += ar[i]*br[j];
    }
    __syncthreads();
  }
  #pragma unroll
  for (int i=0;i<4;++i){
    float4 o; o.x=acc[i][0]; o.y=acc[i][1]; o.z=acc[i][2]; o.w=acc[i][3];
    *(float4*)&C[(size_t)(bm+tr*4+i)*N + bn + tc*4] = o;
  }
}

// ---------------- K3: depthwise causal conv (k=4) + bias + SiLU ---------------
__global__ __launch_bounds__(256) void k_conv(const float* __restrict__ xz,
  const float* __restrict__ cw, const float* __restrict__ cb, float* __restrict__ u)
{
  int g = blockIdx.x*256 + threadIdx.x;
  if (g >= NTOK*DI) return;
  int d = g % DI;
  int tok = g / DI;
  int l = tok % LL;
  float acc = cb[d];
  float w0=cw[d*4+0], w1=cw[d*4+1], w2=cw[d*4+2], w3=cw[d*4+3];
  const float* base = xz + (size_t)tok*768 + d;
  if (l>=3) acc += base[-3*768]*w0;
  if (l>=2) acc += base[-2*768]*w1;
  if (l>=1) acc += base[-1*768]*w2;
  acc += base[0]*w3;
  float sil = acc/(1.0f+__expf(-acc));
  u[g] = sil;
}

// ---------------- pad x_proj_w [384,44] -> [384,64] (zero-pad cols) -----------
__global__ __launch_bounds__(256) void k_padw(const float* __restrict__ W,
  float* __restrict__ Wpad)
{
  int g = blockIdx.x*256 + threadIdx.x;
  if (g >= DI*XDW) return;
  int j = g % XDW, k = g / XDW;
  Wpad[g] = (j < DTR+2*DS) ? W[k*(DTR+2*DS) + j] : 0.f;
}

// ---------------- K4b: delta = softplus(dt @ dt_proj_w + b) ------------------
// dt = x_dbl[:, 0:12]
__global__ __launch_bounds__(256) void k_delta(const float* __restrict__ xdbl,
  const float* __restrict__ W, const float* __restrict__ bias, float* __restrict__ delta)
{
  int g = blockIdx.x*256+threadIdx.x;
  if (g >= NTOK*DI) return;
  int d = g % DI; int tok = g / DI;
  float acc = bias[d];
  const float* dtr = xdbl + (size_t)tok*XDW;
  #pragma unroll
  for (int r=0;r<DTR;++r) acc += dtr[r]*W[r*DI+d];
  float sp = fmaxf(acc,0.f) + log1pf(__expf(-fabsf(acc)));
  delta[g] = sp;
}

// ---------------- K5a: chunk-local scan (h from 0) + running dA product ------
// Bc = x_dbl[:, 12:28]
__global__ __launch_bounds__(256) void k_scanA(const float* __restrict__ delta,
  const float* __restrict__ u, const float* __restrict__ xdbl, const float* __restrict__ Alog,
  float* __restrict__ apb, float* __restrict__ heb)
{
  int g = blockIdx.x*256+threadIdx.x;
  if (g >= BB*NCH*DI) return;
  int d = g % DI;
  int c = (g/DI) % NCH;
  int b = g/(DI*NCH);
  float A[DS], h[DS], ap[DS];
  #pragma unroll
  for (int n=0;n<DS;++n){ A[n] = -__expf(Alog[d*DS+n]); h[n]=0.f; ap[n]=1.f; }
  int t0 = c*CHUNK;
  for (int t=t0; t<t0+CHUNK; ++t){
    size_t tok = (size_t)b*LL + t;
    float dl = delta[tok*DI + d];
    float uu = u[tok*DI + d];
    float du = dl*uu;
    const float* bcr = xdbl + tok*XDW + DTR;
    #pragma unroll
    for (int n=0;n<DS;++n){
      float dA = __expf(dl*A[n]);
      h[n] = dA*h[n] + du*bcr[n];
      ap[n] *= dA;
    }
  }
  size_t off = ((size_t)(b*NCH + c)*DI + d)*DS;
  #pragma unroll
  for (int n=0;n<DS;++n){ apb[off+n]=ap[n]; heb[off+n]=h[n]; }
}

// ---------------- K5b: cross-chunk scan (tiny) -------------------------------
__global__ __launch_bounds__(256) void k_scanB(const float* __restrict__ apb,
  const float* __restrict__ heb, float* __restrict__ hsb)
{
  int g = blockIdx.x*256+threadIdx.x;
  if (g >= BB*DI) return;
  int d = g % DI; int b = g / DI;
  float h[DS];
  #pragma unroll
  for (int n=0;n<DS;++n) h[n]=0.f;
  for (int c=0;c<NCH;++c){
    size_t off = ((size_t)(b*NCH+c)*DI + d)*DS;
    #pragma unroll
    for (int n=0;n<DS;++n) hsb[off+n] = h[n];
    #pragma unroll
    for (int n=0;n<DS;++n) h[n] = apb[off+n]*h[n] + heb[off+n];
  }
}

// ---------------- K5c: re-scan with true h_start, fused epilogue -------------
// Bc = x_dbl[:,12:28], Cc = x_dbl[:,28:44]. outpre aliases delta (safe: same
// element read-then-written by the owning thread only).
__global__ __launch_bounds__(256) void k_scanC(const float* __restrict__ delta_in,
  const float* __restrict__ u, const float* __restrict__ xdbl,
  const float* __restrict__ Alog, const float* __restrict__ Dskip,
  const float* __restrict__ xz, const float* __restrict__ hsb, float* __restrict__ outpre)
{
  int g = blockIdx.x*256+threadIdx.x;
  if (g >= BB*NCH*DI) return;
  int d = g % DI;
  int c = (g/DI) % NCH;
  int b = g/(DI*NCH);
  float A[DS], h[DS];
  size_t off = ((size_t)(b*NCH + c)*DI + d)*DS;
  #pragma unroll
  for (int n=0;n<DS;++n){ A[n] = -__expf(Alog[d*DS+n]); h[n]=hsb[off+n]; }
  float dsk = Dskip[d];
  int t0 = c*CHUNK;
  for (int t=t0; t<t0+CHUNK; ++t){
    size_t tok = (size_t)b*LL + t;
    float dl = delta_in[tok*DI + d];
    float uu = u[tok*DI + d];
    float du = dl*uu;
    const float* bcr = xdbl + tok*XDW + DTR;
    const float* ccr = xdbl + tok*XDW + DTR + DS;
    float y = 0.f;
    #pragma unroll
    for (int n=0;n<DS;++n){
      float dA = __expf(dl*A[n]);
      h[n] = dA*h[n] + du*bcr[n];
      y += h[n]*ccr[n];
    }
    y += uu*dsk;
    float z = xz[tok*768 + 384 + d];
    float sil = z/(1.0f+__expf(-z));
    outpre[tok*DI + d] = y*sil;
  }
}

extern "C" void kernel_launch(void* const* d_in, const int* in_sizes, int n_in,
                              void* d_out, int out_size, void* d_ws, size_t ws_size,
                              hipStream_t stream) {
  const float* x         = (const float*)d_in[0];
  const float* ln_w      = (const float*)d_in[1];
  const float* ln_b      = (const float*)d_in[2];
  const float* in_proj_w = (const float*)d_in[3];
  const float* conv_w    = (const float*)d_in[4];
  const float* conv_b    = (const float*)d_in[5];
  const float* x_proj_w  = (const float*)d_in[6];
  const float* dt_proj_w = (const float*)d_in[7];
  const float* dt_proj_b = (const float*)d_in[8];
  const float* A_log     = (const float*)d_in[9];
  const float* D_skip    = (const float*)d_in[10];
  const float* out_proj_w= (const float*)d_in[11];
  float* out = (float*)d_out;

  float* ws = (float*)d_ws;
  size_t off = 0;
  float* hbuf  = ws + off; off += (size_t)NTOK*DM;      // 2.41M
  float* xz    = ws + off; off += (size_t)NTOK*768;     // 9.63M
  float* ubuf  = ws + off; off += (size_t)NTOK*DI;      // 4.82M
  float* delta = ws + off; off += (size_t)NTOK*DI;      // 4.82M (reused as outpre)
  float* xdbl  = ws + off; off += (size_t)NTOK*XDW;     // 0.80M
  float* wpad  = ws + off; off += (size_t)DI*XDW;       // 24.6K
  float* apb   = ws + off; off += (size_t)BB*NCH*DI*DS; // 1.38M
  float* heb   = ws + off; off += (size_t)BB*NCH*DI*DS;
  float* hsb   = ws + off; off += (size_t)BB*NCH*DI*DS;

  // 1. LayerNorm
  k_ln<<<NTOK, 64, 0, stream>>>(x, ln_w, ln_b, hbuf);
  // 2. in_proj GEMM: [12544,192] @ [192,768]
  {
    dim3 g(768/64, NTOK/64);
    k_sgemm<<<g, 256, 0, stream>>>(hbuf, in_proj_w, xz, NTOK, 768, DM);
  }
  // 3. conv + SiLU
  k_conv<<<(NTOK*DI)/256, 256, 0, stream>>>(xz, conv_w, conv_b, ubuf);
  // 4a. x_proj as padded GEMM: [12544,384] @ [384,64]
  k_padw<<<(DI*XDW)/256, 256, 0, stream>>>(x_proj_w, wpad);
  {
    dim3 g(XDW/64, NTOK/64);
    k_sgemm<<<g, 256, 0, stream>>>(ubuf, wpad, xdbl, NTOK, XDW, DI);
  }
  // 4b. dt_proj + softplus
  k_delta<<<(NTOK*DI)/256, 256, 0, stream>>>(xdbl, dt_proj_w, dt_proj_b, delta);
  // 5. chunked scan
  k_scanA<<<(BB*NCH*DI)/256, 256, 0, stream>>>(delta, ubuf, xdbl, A_log, apb, heb);
  k_scanB<<<(BB*DI)/256, 256, 0, stream>>>(apb, heb, hsb);
  k_scanC<<<(BB*NCH*DI)/256, 256, 0, stream>>>(delta, ubuf, xdbl, A_log, D_skip,
                                               xz, hsb, delta /*outpre in-place*/);
  // 6. out_proj GEMM: [12544,384] @ [384,192] -> d_out
  {
    dim3 g(192/64, NTOK/64);
    k_sgemm<<<g, 256, 0, stream>>>(delta, out_proj_w, out, NTOK, 192, DI);
  }
}

// Round 3
// 252.243 us; speedup vs baseline: 1.5858x; 1.3937x over previous
//
#include <hip/hip_runtime.h>
#include <math.h>

#define DM 192
#define DI 384
#define DS 16
#define DTR 12
#define BB 4
#define LL 3136
#define NTOK (BB*LL)
#define CHUNK 28
#define NCH (LL/CHUNK)
#define XDW 64   // padded x_dbl width (44 real cols: 12 dt, 16 B, 16 C)

__device__ __forceinline__ float warp_sum64(float v){
  #pragma unroll
  for (int m=32;m>=1;m>>=1) v += __shfl_xor(v, m, 64);
  return v;
}

// ---------------- K1: LayerNorm (one wave per token, 3 elems/lane) -------------
__global__ __launch_bounds__(64) void k_ln(const float* __restrict__ x,
    const float* __restrict__ w, const float* __restrict__ b, float* __restrict__ h)
{
  int tok = blockIdx.x;
  int lane = threadIdx.x;
  const float* xr = x + (size_t)tok*DM;
  float v0 = xr[lane], v1 = xr[lane+64], v2 = xr[lane+128];
  float s = warp_sum64(v0+v1+v2);
  float mu = s * (1.0f/DM);
  float d0=v0-mu, d1=v1-mu, d2=v2-mu;
  float s2 = warp_sum64(d0*d0+d1*d1+d2*d2);
  float rs = rsqrtf(s2*(1.0f/DM) + 1e-5f);
  float* hr = h + (size_t)tok*DM;
  hr[lane]     = d0*rs*w[lane]     + b[lane];
  hr[lane+64]  = d1*rs*w[lane+64]  + b[lane+64];
  hr[lane+128] = d2*rs*w[lane+128] + b[lane+128];
}

// ---------------- Tiled fp32 GEMM: C[M,N] = A[M,K] @ B[K,N] -------------------
__global__ __launch_bounds__(256) void k_sgemm(const float* __restrict__ A,
  const float* __restrict__ Bm, float* __restrict__ C, int M, int N, int K)
{
  const int BM=64, BN=64, BK=16;
  __shared__ float As[BK][BM+4];
  __shared__ float Bs[BK][BN];
  int tid = threadIdx.x;
  int bm = blockIdx.y*BM, bn = blockIdx.x*BN;
  int tr = tid/16, tc = tid%16;
  float acc[4][4] = {};
  int a_row = tid/4;
  int a_c4  = (tid%4)*4;
  int b_row = tid/16;
  int b_c4  = (tid%16)*4;
  for (int k0=0;k0<K;k0+=BK){
    float4 av = *(const float4*)&A[(size_t)(bm+a_row)*K + k0 + a_c4];
    As[a_c4+0][a_row]=av.x;
    As[a_c4+1][a_row]=av.y;
    As[a_c4+2][a_row]=av.z;
    As[a_c4+3][a_row]=av.w;
    *(float4*)&Bs[b_row][b_c4] = *(const float4*)&Bm[(size_t)(k0+b_row)*N + bn + b_c4];
    __syncthreads();
    #pragma unroll
    for (int k=0;k<BK;++k){
      float4 a4 = *(const float4*)&As[k][tr*4];
      float4 b4 = *(const float4*)&Bs[k][tc*4];
      float ar[4] = {a4.x,a4.y,a4.z,a4.w};
      float br[4] = {b4.x,b4.y,b4.z,b4.w};
      #pragma unroll
      for (int i=0;i<4;++i)
        #pragma unroll
        for (int j=0;j<4;++j)
          acc[i][j] += ar[i]*br[j];
    }
    __syncthreads();
  }
  #pragma unroll
  for (int i=0;i<4;++i){
    float4 o; o.x=acc[i][0]; o.y=acc[i][1]; o.z=acc[i][2]; o.w=acc[i][3];
    *(float4*)&C[(size_t)(bm+tr*4+i)*N + bn + tc*4] = o;
  }
}

// ---------------- K3: depthwise causal conv (k=4) + bias + SiLU ---------------
__global__ __launch_bounds__(256) void k_conv(const float* __restrict__ xz,
  const float* __restrict__ cw, const float* __restrict__ cb, float* __restrict__ u)
{
  int g = blockIdx.x*256 + threadIdx.x;
  if (g >= NTOK*DI) return;
  int d = g % DI;
  int tok = g / DI;
  int l = tok % LL;
  float acc = cb[d];
  float w0=cw[d*4+0], w1=cw[d*4+1], w2=cw[d*4+2], w3=cw[d*4+3];
  const float* base = xz + (size_t)tok*768 + d;
  if (l>=3) acc += base[-3*768]*w0;
  if (l>=2) acc += base[-2*768]*w1;
  if (l>=1) acc += base[-1*768]*w2;
  acc += base[0]*w3;
  float sil = acc/(1.0f+__expf(-acc));
  u[g] = sil;
}

// ---------------- pad x_proj_w [384,44] -> [384,64] (zero-pad cols) -----------
__global__ __launch_bounds__(256) void k_padw(const float* __restrict__ W,
  float* __restrict__ Wpad)
{
  int g = blockIdx.x*256 + threadIdx.x;
  if (g >= DI*XDW) return;
  int j = g % XDW, k = g / XDW;
  Wpad[g] = (j < DTR+2*DS) ? W[k*(DTR+2*DS) + j] : 0.f;
}

// ---------------- K4b: delta = softplus(dt @ dt_proj_w + b) ------------------
__global__ __launch_bounds__(256) void k_delta(const float* __restrict__ xdbl,
  const float* __restrict__ W, const float* __restrict__ bias, float* __restrict__ delta)
{
  int g = blockIdx.x*256+threadIdx.x;
  if (g >= NTOK*DI) return;
  int d = g % DI; int tok = g / DI;
  float acc = bias[d];
  const float* dtr = xdbl + (size_t)tok*XDW;
  #pragma unroll
  for (int r=0;r<DTR;++r) acc += dtr[r]*W[r*DI+d];
  float sp = fmaxf(acc,0.f) + log1pf(__expf(-fabsf(acc)));
  delta[g] = sp;
}

// ---------------- K5a: chunk-local scan, 4 threads per (b,c,d), 4 states each -
__global__ __launch_bounds__(256) void k_scanA(const float* __restrict__ delta,
  const float* __restrict__ u, const float* __restrict__ xdbl, const float* __restrict__ Alog,
  float* __restrict__ apb, float* __restrict__ heb)
{
  int g = blockIdx.x*256+threadIdx.x;
  if (g >= BB*NCH*DI*4) return;
  int sg = g & 3;
  int d  = (g>>2) % DI;
  int c  = ((g>>2)/DI) % NCH;
  int b  = g/(4*DI*NCH);
  float A[4], h[4], ap[4];
  #pragma unroll
  for (int n=0;n<4;++n){ A[n] = -__expf(Alog[d*DS + sg*4 + n]); h[n]=0.f; ap[n]=1.f; }
  int t0 = c*CHUNK;
  for (int t=t0; t<t0+CHUNK; ++t){
    size_t tok = (size_t)b*LL + t;
    float dl = delta[tok*DI + d];
    float du = dl * u[tok*DI + d];
    float4 bc4 = *(const float4*)&xdbl[tok*XDW + DTR + sg*4];
    float bc[4] = {bc4.x,bc4.y,bc4.z,bc4.w};
    #pragma unroll
    for (int n=0;n<4;++n){
      float dA = __expf(dl*A[n]);
      h[n] = dA*h[n] + du*bc[n];
      ap[n] *= dA;
    }
  }
  size_t off = ((size_t)((b*NCH + c)*DI) + d)*DS + sg*4;
  float4 o1; o1.x=ap[0]; o1.y=ap[1]; o1.z=ap[2]; o1.w=ap[3];
  float4 o2; o2.x=h[0];  o2.y=h[1];  o2.z=h[2];  o2.w=h[3];
  *(float4*)&apb[off] = o1;
  *(float4*)&heb[off] = o2;
}

// ---------------- K5b: cross-chunk scan; converts apb -> h_start in place ----
__global__ __launch_bounds__(256) void k_scanB(float* __restrict__ apb,
  const float* __restrict__ heb)
{
  int g = blockIdx.x*256+threadIdx.x;
  if (g >= BB*DI*4) return;
  int sg = g&3; int d = (g>>2)%DI; int b = (g>>2)/DI;
  float h0=0.f,h1=0.f,h2=0.f,h3=0.f;
  for (int c=0;c<NCH;++c){
    size_t off = ((size_t)((b*NCH+c)*DI)+d)*DS + sg*4;
    float4 ap = *(const float4*)&apb[off];
    float4 he = *(const float4*)&heb[off];
    float4 hs; hs.x=h0; hs.y=h1; hs.z=h2; hs.w=h3;
    *(float4*)&apb[off] = hs;
    h0 = ap.x*h0 + he.x;
    h1 = ap.y*h1 + he.y;
    h2 = ap.z*h2 + he.z;
    h3 = ap.w*h3 + he.w;
  }
}

// ---------------- K5c: re-scan with true h_start, fused epilogue -------------
// outpre aliases delta_in: the quad reads delta at (tok,d) in lockstep before
// the sg==0 lane's store to the same element later in the same iteration.
__global__ __launch_bounds__(256) void k_scanC(const float* __restrict__ delta_in,
  const float* __restrict__ u, const float* __restrict__ xdbl,
  const float* __restrict__ Alog, const float* __restrict__ Dskip,
  const float* __restrict__ xz, const float* __restrict__ hstart, float* __restrict__ outpre)
{
  int g = blockIdx.x*256+threadIdx.x;
  if (g >= BB*NCH*DI*4) return;
  int sg = g & 3;
  int d  = (g>>2) % DI;
  int c  = ((g>>2)/DI) % NCH;
  int b  = g/(4*DI*NCH);
  size_t off = ((size_t)((b*NCH + c)*DI) + d)*DS + sg*4;
  float4 h4 = *(const float4*)&hstart[off];
  float h[4] = {h4.x,h4.y,h4.z,h4.w};
  float A[4];
  #pragma unroll
  for (int n=0;n<4;++n) A[n] = -__expf(Alog[d*DS + sg*4 + n]);
  float dsk = Dskip[d];
  int t0 = c*CHUNK;
  for (int t=t0; t<t0+CHUNK; ++t){
    size_t tok = (size_t)b*LL + t;
    float dl = delta_in[tok*DI + d];
    float uu = u[tok*DI + d];
    float du = dl*uu;
    float4 bc4 = *(const float4*)&xdbl[tok*XDW + DTR + sg*4];
    float4 cc4 = *(const float4*)&xdbl[tok*XDW + DTR + DS + sg*4];
    float y;
    {
      float dA0=__expf(dl*A[0]); h[0]=dA0*h[0]+du*bc4.x; y  = h[0]*cc4.x;
      float dA1=__expf(dl*A[1]); h[1]=dA1*h[1]+du*bc4.y; y += h[1]*cc4.y;
      float dA2=__expf(dl*A[2]); h[2]=dA2*h[2]+du*bc4.z; y += h[2]*cc4.z;
      float dA3=__expf(dl*A[3]); h[3]=dA3*h[3]+du*bc4.w; y += h[3]*cc4.w;
    }
    y += __shfl_xor(y, 1, 64);
    y += __shfl_xor(y, 2, 64);
    if (sg == 0){
      y += uu*dsk;
      float z = xz[tok*768 + 384 + d];
      float sil = z/(1.0f+__expf(-z));
      outpre[tok*DI + d] = y*sil;
    }
  }
}

extern "C" void kernel_launch(void* const* d_in, const int* in_sizes, int n_in,
                              void* d_out, int out_size, void* d_ws, size_t ws_size,
                              hipStream_t stream) {
  const float* x         = (const float*)d_in[0];
  const float* ln_w      = (const float*)d_in[1];
  const float* ln_b      = (const float*)d_in[2];
  const float* in_proj_w = (const float*)d_in[3];
  const float* conv_w    = (const float*)d_in[4];
  const float* conv_b    = (const float*)d_in[5];
  const float* x_proj_w  = (const float*)d_in[6];
  const float* dt_proj_w = (const float*)d_in[7];
  const float* dt_proj_b = (const float*)d_in[8];
  const float* A_log     = (const float*)d_in[9];
  const float* D_skip    = (const float*)d_in[10];
  const float* out_proj_w= (const float*)d_in[11];
  float* out = (float*)d_out;

  float* ws = (float*)d_ws;
  size_t off = 0;
  float* hbuf  = ws + off; off += (size_t)NTOK*DM;      // 2.41M
  float* xz    = ws + off; off += (size_t)NTOK*768;     // 9.63M
  float* ubuf  = ws + off; off += (size_t)NTOK*DI;      // 4.82M
  float* delta = ws + off; off += (size_t)NTOK*DI;      // 4.82M (reused as outpre)
  float* xdbl  = ws + off; off += (size_t)NTOK*XDW;     // 0.80M
  float* wpad  = ws + off; off += (size_t)DI*XDW;       // 24.6K
  float* apb   = ws + off; off += (size_t)BB*NCH*DI*DS; // 2.75M (-> h_start)
  float* heb   = ws + off; off += (size_t)BB*NCH*DI*DS; // 2.75M

  // 1. LayerNorm
  k_ln<<<NTOK, 64, 0, stream>>>(x, ln_w, ln_b, hbuf);
  // 2. in_proj GEMM: [12544,192] @ [192,768]
  {
    dim3 g(768/64, NTOK/64);
    k_sgemm<<<g, 256, 0, stream>>>(hbuf, in_proj_w, xz, NTOK, 768, DM);
  }
  // 3. conv + SiLU
  k_conv<<<(NTOK*DI)/256, 256, 0, stream>>>(xz, conv_w, conv_b, ubuf);
  // 4a. x_proj as padded GEMM: [12544,384] @ [384,64]
  k_padw<<<(DI*XDW)/256, 256, 0, stream>>>(x_proj_w, wpad);
  {
    dim3 g(XDW/64, NTOK/64);
    k_sgemm<<<g, 256, 0, stream>>>(ubuf, wpad, xdbl, NTOK, XDW, DI);
  }
  // 4b. dt_proj + softplus
  k_delta<<<(NTOK*DI)/256, 256, 0, stream>>>(xdbl, dt_proj_w, dt_proj_b, delta);
  // 5. chunked scan (4-way state split)
  k_scanA<<<(BB*NCH*DI*4)/256, 256, 0, stream>>>(delta, ubuf, xdbl, A_log, apb, heb);
  k_scanB<<<(BB*DI*4+255)/256, 256, 0, stream>>>(apb, heb);
  k_scanC<<<(BB*NCH*DI*4)/256, 256, 0, stream>>>(delta, ubuf, xdbl, A_log, D_skip,
                                                 xz, apb, delta /*outpre in-place*/);
  // 6. out_proj GEMM: [12544,384] @ [384,192] -> d_out
  {
    dim3 g(192/64, NTOK/64);
    k_sgemm<<<g, 256, 0, stream>>>(delta, out_proj_w, out, NTOK, 192, DI);
  }
}

// Round 5
// 185.621 us; speedup vs baseline: 2.1550x; 1.3589x over previous
//
#include <hip/hip_runtime.h>
#include <math.h>

#define DM 192
#define DI 384
#define DS 16
#define DTR 12
#define BB 4
#define LL 3136
#define NTOK (BB*LL)
#define CHUNK 28
#define NCH (LL/CHUNK)
#define XDW 64   // padded x_dbl width (44 real cols: 12 dt, 16 B, 16 C)

typedef _Float16 half8 __attribute__((ext_vector_type(8)));
typedef float f32x4 __attribute__((ext_vector_type(4)));

__device__ __forceinline__ float warp_sum64(float v){
  #pragma unroll
  for (int m=32;m>=1;m>>=1) v += __shfl_xor(v, m, 64);
  return v;
}

// ---------------- K1: LayerNorm -> fp16 h ------------------------------------
__global__ __launch_bounds__(64) void k_ln(const float* __restrict__ x,
    const float* __restrict__ w, const float* __restrict__ b, _Float16* __restrict__ h)
{
  int tok = blockIdx.x;
  int lane = threadIdx.x;
  const float* xr = x + (size_t)tok*DM;
  float v0 = xr[lane], v1 = xr[lane+64], v2 = xr[lane+128];
  float s = warp_sum64(v0+v1+v2);
  float mu = s * (1.0f/DM);
  float d0=v0-mu, d1=v1-mu, d2=v2-mu;
  float s2 = warp_sum64(d0*d0+d1*d1+d2*d2);
  float rs = rsqrtf(s2*(1.0f/DM) + 1e-5f);
  _Float16* hr = h + (size_t)tok*DM;
  hr[lane]     = (_Float16)(d0*rs*w[lane]     + b[lane]);
  hr[lane+64]  = (_Float16)(d1*rs*w[lane+64]  + b[lane+64]);
  hr[lane+128] = (_Float16)(d2*rs*w[lane+128] + b[lane+128]);
}

// ---------------- weight convert + transpose (+ optional col pad) ------------
// Wt[n][k] = (n < realN) ? W[k][n] : 0     (W is [Kdim][realN] row-major fp32)
__global__ __launch_bounds__(256) void k_w16t(const float* __restrict__ W,
  _Float16* __restrict__ Wt, int Kdim, int Ndim, int realN)
{
  int g = blockIdx.x*256 + threadIdx.x;
  if (g >= Kdim*Ndim) return;
  int k = g % Kdim, n = g / Kdim;
  Wt[g] = (n < realN) ? (_Float16)W[(size_t)k*realN + n] : (_Float16)0.f;
}

// ---------------- fp16 MFMA GEMM: C[M,N](f32) = A[M,K] @ Bt[N,K]^T -----------
// BM=BN=64, BK=32, 256 threads = 4 waves, each wave one 32x32 quadrant,
// 2x2 grid of mfma_f32_16x16x32_f16 fragments.
__global__ __launch_bounds__(256) void k_hgemm(const _Float16* __restrict__ A,
  const _Float16* __restrict__ Bt, float* __restrict__ C, int M, int N, int K)
{
  __shared__ _Float16 As[64][40];
  __shared__ _Float16 Bs[64][40];
  int tid = threadIdx.x;
  int bm = blockIdx.y*64, bn = blockIdx.x*64;
  int wave = tid>>6, lane = tid&63;
  int wr = (wave>>1)*32, wc = (wave&1)*32;
  f32x4 acc00 = {0.f,0.f,0.f,0.f}, acc01 = {0.f,0.f,0.f,0.f};
  f32x4 acc10 = {0.f,0.f,0.f,0.f}, acc11 = {0.f,0.f,0.f,0.f};
  int sr = tid>>2;           // staging row 0..63
  int sc = (tid&3)*8;        // staging chunk (halves) 0,8,16,24
  int fr = lane&15;          // fragment row/col within 16
  int fk = (lane>>4)*8;      // k-offset of this lane's 8 contiguous elems

  for (int k0=0; k0<K; k0+=32){
    *(float4*)&As[sr][sc] = *(const float4*)&A[(size_t)(bm+sr)*K + k0 + sc];
    *(float4*)&Bs[sr][sc] = *(const float4*)&Bt[(size_t)(bn+sr)*K + k0 + sc];
    __syncthreads();
    half8 a0 = *(const half8*)&As[wr + fr][fk];
    half8 a1 = *(const half8*)&As[wr + 16 + fr][fk];
    half8 b0 = *(const half8*)&Bs[wc + fr][fk];
    half8 b1 = *(const half8*)&Bs[wc + 16 + fr][fk];
    acc00 = __builtin_amdgcn_mfma_f32_16x16x32_f16(a0, b0, acc00, 0, 0, 0);
    acc01 = __builtin_amdgcn_mfma_f32_16x16x32_f16(a0, b1, acc01, 0, 0, 0);
    acc10 = __builtin_amdgcn_mfma_f32_16x16x32_f16(a1, b0, acc10, 0, 0, 0);
    acc11 = __builtin_amdgcn_mfma_f32_16x16x32_f16(a1, b1, acc11, 0, 0, 0);
    __syncthreads();
  }
  // C/D layout: col = lane&15, row = (lane>>4)*4 + reg  [m89-verified]
  int rbase = (lane>>4)*4;
  #pragma unroll
  for (int q=0;q<4;++q){
    size_t row0 = (size_t)(bm + wr + rbase + q)*N + bn + wc;
    C[row0 + fr]           = acc00[q];
    C[row0 + 16 + fr]      = acc01[q];
    size_t row1 = (size_t)(bm + wr + 16 + rbase + q)*N + bn + wc;
    C[row1 + fr]           = acc10[q];
    C[row1 + 16 + fr]      = acc11[q];
  }
}

// ---------------- K3: depthwise causal conv (k=4) + bias + SiLU -> fp16 u ----
__global__ __launch_bounds__(256) void k_conv(const float* __restrict__ xz,
  const float* __restrict__ cw, const float* __restrict__ cb, _Float16* __restrict__ u)
{
  int g = blockIdx.x*256 + threadIdx.x;
  if (g >= NTOK*DI) return;
  int d = g % DI;
  int tok = g / DI;
  int l = tok % LL;
  float acc = cb[d];
  float w0=cw[d*4+0], w1=cw[d*4+1], w2=cw[d*4+2], w3=cw[d*4+3];
  const float* base = xz + (size_t)tok*768 + d;
  if (l>=3) acc += base[-3*768]*w0;
  if (l>=2) acc += base[-2*768]*w1;
  if (l>=1) acc += base[-1*768]*w2;
  acc += base[0]*w3;
  float sil = acc/(1.0f+__expf(-acc));
  u[g] = (_Float16)sil;
}

// ---------------- K4b: delta = softplus(dt @ dt_proj_w + b) ------------------
__global__ __launch_bounds__(256) void k_delta(const float* __restrict__ xdbl,
  const float* __restrict__ W, const float* __restrict__ bias, float* __restrict__ delta)
{
  int g = blockIdx.x*256+threadIdx.x;
  if (g >= NTOK*DI) return;
  int d = g % DI; int tok = g / DI;
  float acc = bias[d];
  const float* dtr = xdbl + (size_t)tok*XDW;
  #pragma unroll
  for (int r=0;r<DTR;++r) acc += dtr[r]*W[r*DI+d];
  float sp = fmaxf(acc,0.f) + log1pf(__expf(-fabsf(acc)));
  delta[g] = sp;
}

// ---------------- K5a: chunk-local scan, 4 threads per (b,c,d) ---------------
__global__ __launch_bounds__(256) void k_scanA(const float* __restrict__ delta,
  const _Float16* __restrict__ u, const float* __restrict__ xdbl,
  const float* __restrict__ Alog, float* __restrict__ apb, float* __restrict__ heb)
{
  int g = blockIdx.x*256+threadIdx.x;
  if (g >= BB*NCH*DI*4) return;
  int sg = g & 3;
  int d  = (g>>2) % DI;
  int c  = ((g>>2)/DI) % NCH;
  int b  = g/(4*DI*NCH);
  float A[4], h[4], ap[4];
  #pragma unroll
  for (int n=0;n<4;++n){ A[n] = -__expf(Alog[d*DS + sg*4 + n]); h[n]=0.f; ap[n]=1.f; }
  int t0 = c*CHUNK;
  for (int t=t0; t<t0+CHUNK; ++t){
    size_t tok = (size_t)b*LL + t;
    float dl = delta[tok*DI + d];
    float du = dl * (float)u[tok*DI + d];
    float4 bc4 = *(const float4*)&xdbl[tok*XDW + DTR + sg*4];
    float bc[4] = {bc4.x,bc4.y,bc4.z,bc4.w};
    #pragma unroll
    for (int n=0;n<4;++n){
      float dA = __expf(dl*A[n]);
      h[n] = dA*h[n] + du*bc[n];
      ap[n] *= dA;
    }
  }
  size_t off = ((size_t)((b*NCH + c)*DI) + d)*DS + sg*4;
  float4 o1; o1.x=ap[0]; o1.y=ap[1]; o1.z=ap[2]; o1.w=ap[3];
  float4 o2; o2.x=h[0];  o2.y=h[1];  o2.z=h[2];  o2.w=h[3];
  *(float4*)&apb[off] = o1;
  *(float4*)&heb[off] = o2;
}

// ---------------- K5b: cross-chunk scan; converts apb -> h_start in place ----
__global__ __launch_bounds__(256) void k_scanB(float* __restrict__ apb,
  const float* __restrict__ heb)
{
  int g = blockIdx.x*256+threadIdx.x;
  if (g >= BB*DI*4) return;
  int sg = g&3; int d = (g>>2)%DI; int b = (g>>2)/DI;
  float h0=0.f,h1=0.f,h2=0.f,h3=0.f;
  for (int c=0;c<NCH;++c){
    size_t off = ((size_t)((b*NCH+c)*DI)+d)*DS + sg*4;
    float4 ap = *(const float4*)&apb[off];
    float4 he = *(const float4*)&heb[off];
    float4 hs; hs.x=h0; hs.y=h1; hs.z=h2; hs.w=h3;
    *(float4*)&apb[off] = hs;
    h0 = ap.x*h0 + he.x;
    h1 = ap.y*h1 + he.y;
    h2 = ap.z*h2 + he.z;
    h3 = ap.w*h3 + he.w;
  }
}

// ---------------- K5c: re-scan with true h_start, fused epilogue -> fp16 -----
__global__ __launch_bounds__(256) void k_scanC(const float* __restrict__ delta_in,
  const _Float16* __restrict__ u, const float* __restrict__ xdbl,
  const float* __restrict__ Alog, const float* __restrict__ Dskip,
  const float* __restrict__ xz, const float* __restrict__ hstart,
  _Float16* __restrict__ outpre)
{
  int g = blockIdx.x*256+threadIdx.x;
  if (g >= BB*NCH*DI*4) return;
  int sg = g & 3;
  int d  = (g>>2) % DI;
  int c  = ((g>>2)/DI) % NCH;
  int b  = g/(4*DI*NCH);
  size_t off = ((size_t)((b*NCH + c)*DI) + d)*DS + sg*4;
  float4 h4 = *(const float4*)&hstart[off];
  float h[4] = {h4.x,h4.y,h4.z,h4.w};
  float A[4];
  #pragma unroll
  for (int n=0;n<4;++n) A[n] = -__expf(Alog[d*DS + sg*4 + n]);
  float dsk = Dskip[d];
  int t0 = c*CHUNK;
  for (int t=t0; t<t0+CHUNK; ++t){
    size_t tok = (size_t)b*LL + t;
    float dl = delta_in[tok*DI + d];
    float uu = (float)u[tok*DI + d];
    float du = dl*uu;
    float4 bc4 = *(const float4*)&xdbl[tok*XDW + DTR + sg*4];
    float4 cc4 = *(const float4*)&xdbl[tok*XDW + DTR + DS + sg*4];
    float y;
    {
      float dA0=__expf(dl*A[0]); h[0]=dA0*h[0]+du*bc4.x; y  = h[0]*cc4.x;
      float dA1=__expf(dl*A[1]); h[1]=dA1*h[1]+du*bc4.y; y += h[1]*cc4.y;
      float dA2=__expf(dl*A[2]); h[2]=dA2*h[2]+du*bc4.z; y += h[2]*cc4.z;
      float dA3=__expf(dl*A[3]); h[3]=dA3*h[3]+du*bc4.w; y += h[3]*cc4.w;
    }
    y += __shfl_xor(y, 1, 64);
    y += __shfl_xor(y, 2, 64);
    if (sg == 0){
      y += uu*dsk;
      float z = xz[tok*768 + 384 + d];
      float sil = z/(1.0f+__expf(-z));
      outpre[tok*DI + d] = (_Float16)(y*sil);
    }
  }
}

extern "C" void kernel_launch(void* const* d_in, const int* in_sizes, int n_in,
                              void* d_out, int out_size, void* d_ws, size_t ws_size,
                              hipStream_t stream) {
  const float* x         = (const float*)d_in[0];
  const float* ln_w      = (const float*)d_in[1];
  const float* ln_b      = (const float*)d_in[2];
  const float* in_proj_w = (const float*)d_in[3];
  const float* conv_w    = (const float*)d_in[4];
  const float* conv_b    = (const float*)d_in[5];
  const float* x_proj_w  = (const float*)d_in[6];
  const float* dt_proj_w = (const float*)d_in[7];
  const float* dt_proj_b = (const float*)d_in[8];
  const float* A_log     = (const float*)d_in[9];
  const float* D_skip    = (const float*)d_in[10];
  const float* out_proj_w= (const float*)d_in[11];
  float* out = (float*)d_out;

  float* ws = (float*)d_ws;
  size_t off = 0;
  float* xz    = ws + off; off += (size_t)NTOK*768;       // f32 38.5MB
  float* delta = ws + off; off += (size_t)NTOK*DI;        // f32 19.3MB
  float* xdbl  = ws + off; off += (size_t)NTOK*XDW;       // f32 3.2MB
  float* apb   = ws + off; off += (size_t)BB*NCH*DI*DS;   // f32 11MB (-> h_start)
  float* heb   = ws + off; off += (size_t)BB*NCH*DI*DS;   // f32 11MB
  _Float16* h16   = (_Float16*)(ws + off); off += (size_t)NTOK*DM/2;   // f16 4.8MB
  _Float16* u16   = (_Float16*)(ws + off); off += (size_t)NTOK*DI/2;   // f16 9.6MB
  _Float16* op16  = (_Float16*)(ws + off); off += (size_t)NTOK*DI/2;   // f16 9.6MB
  _Float16* wtin  = (_Float16*)(ws + off); off += (size_t)768*DM/2;
  _Float16* wtxp  = (_Float16*)(ws + off); off += (size_t)XDW*DI/2;
  _Float16* wtout = (_Float16*)(ws + off); off += (size_t)DM*DI/2;

  // 0. weight convert+transpose (f16, Wt[N][K])
  k_w16t<<<(768*DM+255)/256, 256, 0, stream>>>(in_proj_w,  wtin,  DM, 768, 768);
  k_w16t<<<(XDW*DI+255)/256, 256, 0, stream>>>(x_proj_w,   wtxp,  DI, XDW, DTR+2*DS);
  k_w16t<<<(DM*DI+255)/256, 256, 0, stream>>>(out_proj_w, wtout, DI, DM,  DM);
  // 1. LayerNorm -> f16
  k_ln<<<NTOK, 64, 0, stream>>>(x, ln_w, ln_b, h16);
  // 2. in_proj MFMA GEMM: [12544,192] @ [192,768] -> f32 xz
  {
    dim3 g(768/64, NTOK/64);
    k_hgemm<<<g, 256, 0, stream>>>(h16, wtin, xz, NTOK, 768, DM);
  }
  // 3. conv + SiLU -> f16 u
  k_conv<<<(NTOK*DI)/256, 256, 0, stream>>>(xz, conv_w, conv_b, u16);
  // 4a. x_proj MFMA GEMM: [12544,384] @ [384,64] -> f32 xdbl
  {
    dim3 g(XDW/64, NTOK/64);
    k_hgemm<<<g, 256, 0, stream>>>(u16, wtxp, xdbl, NTOK, XDW, DI);
  }
  // 4b. dt_proj + softplus
  k_delta<<<(NTOK*DI)/256, 256, 0, stream>>>(xdbl, dt_proj_w, dt_proj_b, delta);
  // 5. chunked scan (4-way state split)
  k_scanA<<<(BB*NCH*DI*4)/256, 256, 0, stream>>>(delta, u16, xdbl, A_log, apb, heb);
  k_scanB<<<(BB*DI*4+255)/256, 256, 0, stream>>>(apb, heb);
  k_scanC<<<(BB*NCH*DI*4)/256, 256, 0, stream>>>(delta, u16, xdbl, A_log, D_skip,
                                                 xz, apb, op16);
  // 6. out_proj MFMA GEMM: [12544,384] @ [384,192] -> d_out (f32)
  {
    dim3 g(DM/64, NTOK/64);
    k_hgemm<<<g, 256, 0, stream>>>(op16, wtout, out, NTOK, DM, DI);
  }
}